// Round 4
// baseline (376.808 us; speedup 1.0000x reference)
//
#include <hip/hip_runtime.h>
#include <hip/hip_bf16.h>

#define N_NODES 100000
#define N_EDGES 1000000
#define DIM 64
#define N_GRAPHS 256
#define OUT_DIM 10
#define BN_EPS 1e-5f

#define LAYER_BLOCKS ((N_NODES + 63) / 64)   // 1563 (4-wave blocks — R12 form)
#define PAD 24                               // slots per node; P(deg>24)~4e-5
#define SPILL_CAP 8192
#define NPART 8                              // dst partitions (one per XCD)
#define PART_SZ ((N_NODES + NPART - 1) / NPART)   // 12500

// ---- grid-stride fill geometry (R3 form, kept: neutral vs 31K blocks but
// dispatch-lighter; fill is at its transaction floor either way) ----
#define EDGE_CHUNKS ((N_EDGES + 255) / 256)                    // 3907
#define FILLB_PER_PART 256
#define FILL_GRID (NPART * FILLB_PER_PART)                     // 2048
#define XC_BLOCKS ((N_NODES * 16 + 255) / 256)                 // 6250
#define FF_BLOCKS (FILL_GRID + XC_BLOCKS + 6 + 1)              // 8305

// ---- zero kernel geometry ----
#define Z4A 96                       // SUMS: 384 floats as uint4
#define Z4B 25008                    // DEG+NSPILL+PFCNT: 100032 ints as uint4
#define ZLIN_BLOCKS ((Z4A + Z4B + 255) / 256)                  // 99
#define SEG_BLOCKS ((N_NODES + 255) / 256)                     // 391
#define ZERO_BLOCKS (ZLIN_BLOCKS + SEG_BLOCKS)                 // 490

typedef __bf16 bf16x8 __attribute__((ext_vector_type(8)));
typedef float f32x4 __attribute__((ext_vector_type(4)));

__device__ __forceinline__ float bfu(unsigned short u) {
    return (float)__builtin_bit_cast(__bf16, u);
}

// ---------------------------------------------------------------------------
// Zero + segment-boundary kernel (tiny; precedes everything).
// ---------------------------------------------------------------------------
__global__ __launch_bounds__(256) void zero_kernel(
    uint4* __restrict__ za, uint4* __restrict__ zb,
    const int* __restrict__ batch, int* __restrict__ bstart)
{
    const int bid = blockIdx.x;
    const int tid = threadIdx.x;
    if (bid < ZLIN_BLOCKS) {
        int i = bid * 256 + tid;
        uint4 z = {0u, 0u, 0u, 0u};
        if (i < Z4A) za[i] = z;
        else if (i < Z4A + Z4B) zb[i - Z4A] = z;
    } else {
        int n = (bid - ZLIN_BLOCKS) * 256 + tid;
        if (n < N_NODES) {
            int b = batch[n];
            int bp = (n == 0) ? -1 : batch[n - 1];
            for (int gg = bp + 1; gg <= b; ++gg) bstart[gg] = n;
            if (n == N_NODES - 1)
                for (int gg = b + 1; gg <= N_GRAPHS; ++gg) bstart[gg] = N_NODES;
        }
    }
}

// ---------------------------------------------------------------------------
// Fused fill + prep-compute (R3 grid-stride form, unchanged).
// ---------------------------------------------------------------------------
__global__ __launch_bounds__(256) void fill_kernel(
    const int* __restrict__ ei, int* __restrict__ deg,
    int* __restrict__ esrc, int* __restrict__ nspill, int* __restrict__ spill,
    const float* __restrict__ w1, const float* __restrict__ w2,
    __bf16* __restrict__ wf,
    const float4* __restrict__ x0, ushort4* __restrict__ xp4,
    unsigned short* __restrict__ xp_s, unsigned short* __restrict__ xq_s,
    unsigned short* __restrict__ xs_s)
{
    const int bid = blockIdx.x;
    const int tid = threadIdx.x;

    if (bid < FILL_GRID) {
        // ---- grid-stride XCD-partitioned edge fill ----
        const int part = bid & (NPART - 1);
        const int lo = part * PART_SZ;
        for (int c = bid >> 3; c < EDGE_CHUNKS; c += FILLB_PER_PART) {
            int e = c * 256 + tid;
            if (e >= N_EDGES) continue;            // last chunk partial
            int dst = ei[N_EDGES + e];
            if (dst < lo || dst >= lo + PART_SZ) continue;
            int src = ei[e];
            int pos = atomicAdd(&deg[dst], 1);
            if (pos < PAD) {
                esrc[dst * PAD + pos] = src;
            } else {
                int sp = atomicAdd(nspill, 1);
                if (sp < SPILL_CAP) { spill[2 * sp] = dst; spill[2 * sp + 1] = src; }
            }
        }
    } else if (bid < FILL_GRID + XC_BLOCKS) {
        // ---- x0 -> bf16 copy XP ----
        int t = (bid - FILL_GRID) * 256 + tid;
        if (t < N_NODES * 16) {
            float4 v = x0[t];
            ushort4 o;
            o.x = __builtin_bit_cast(unsigned short, (__bf16)v.x);
            o.y = __builtin_bit_cast(unsigned short, (__bf16)v.y);
            o.z = __builtin_bit_cast(unsigned short, (__bf16)v.z);
            o.w = __builtin_bit_cast(unsigned short, (__bf16)v.w);
            xp4[t] = o;
        }
    } else if (bid < FILL_GRID + XC_BLOCKS + 6) {
        // ---- weight split: fp32 W -> bf16 hi/lo, MFMA B-frag order ----
        int wb = bid - FILL_GRID - XC_BLOCKS;
        int L = wb >> 1, mat = wb & 1;
        const float* w = (mat ? w2 : w1) + L * 4096;
        __bf16* dst = wf + wb * 8192;
#pragma unroll
        for (int r = 0; r < 2; ++r) {
            int idx = tid + 256 * r;              // (kstep*4+nt)*64 + lane
            int lane = idx & 63;
            int kt = idx >> 6;
            int kstep = kt >> 2, nt = kt & 3;
            int n = nt * 16 + (lane & 15);
            int kbase = kstep * 32 + (lane >> 4) * 8;
#pragma unroll
            for (int j = 0; j < 8; ++j) {
                float v = w[(kbase + j) * 64 + n];
                __bf16 hi = (__bf16)v;
                dst[idx * 8 + j] = hi;
                dst[4096 + idx * 8 + j] = (__bf16)(v - (float)hi);
            }
        }
    } else {
        // ---- sentinel rows: XP[N]=0, XQ[N]=XS[N]=bf16(-inf) ----
        if (tid < 64) {
            xp_s[tid] = 0;                        // bf16 +0
            xq_s[tid] = 0xFF80;                   // bf16 -inf
            xs_s[tid] = 0xFF80;
        }
    }
}

// ---------------------------------------------------------------------------
// Gather batch: NC 4-slot chunks starting at chunk cbase. Straight-line
// load batch (all idx loads, then all row loads, then accumulate) preserves
// the MLP of the old fixed-12 path. USE_C0: chunk cbase's indices arrive
// pre-loaded (the per-node prefetch register). Pad slots (>= deg) hit the
// sentinel row and contribute exactly +0.0f, so hval is bit-identical to
// the old fixed-chunk sum.
// ---------------------------------------------------------------------------
template <int NC, bool USE_C0, bool BN>
__device__ __forceinline__ float gatherN(
    uint4 c0, const uint4* __restrict__ ep4, int cbase,
    const unsigned short* __restrict__ xb, int lane,
    float scale, float shift)
{
    unsigned idx[NC * 4];
#pragma unroll
    for (int k = 0; k < NC; ++k) {
        uint4 c = (USE_C0 && k == 0) ? c0 : ep4[cbase + k];
        idx[4 * k + 0] = c.x; idx[4 * k + 1] = c.y;
        idx[4 * k + 2] = c.z; idx[4 * k + 3] = c.w;
    }
    unsigned short u[NC * 4];
#pragma unroll
    for (int j = 0; j < NC * 4; ++j) {
        unsigned s = idx[j];
        s = (s < (unsigned)N_NODES) ? s : (unsigned)N_NODES;
        u[j] = xb[(size_t)s * 64 + lane];
    }
    float acc = 0.0f;
#pragma unroll
    for (int j = 0; j < NC * 4; ++j) {
        float t = bfu(u[j]);
        if (BN) t = fmaxf(fmaf(t, scale, shift), 0.0f);
        acc += t;
    }
    return acc;
}

// ---------------------------------------------------------------------------
// FUSED GIN layer — R12 GEMM/BN structure unchanged. NEW this round: the
// gather reads exactly ceil(min(deg,24)/4) 4-slot chunks instead of fixed
// 12 (+12 if deg>12): E[rows/node] 14.5 -> 11.5 (-21% gather lines).
// All chunk-count branches are wave-uniform (deg is per-node, shared by the
// wave); batches split at 3 chunks to cap register liveness at the old
// 12-load peak. Summed values are bit-identical (pads add exactly 0.0f).
// ---------------------------------------------------------------------------
template <bool BN>
__global__ __launch_bounds__(256) void layer_kernel(
    const unsigned short* __restrict__ xb,
    const float* __restrict__ sums_in, const float* __restrict__ gamma,
    const float* __restrict__ beta,
    const int* __restrict__ deg, const int* __restrict__ esrc,
    const int* __restrict__ nspill, const int* __restrict__ spill,
    unsigned short* __restrict__ xbout,
    const __bf16* __restrict__ wf1, const __bf16* __restrict__ wf2,
    const float* __restrict__ b1, const float* __restrict__ b2,
    const float* __restrict__ eps_all, int layer,
    float* __restrict__ sums_out)
{
    __shared__ __attribute__((aligned(16))) unsigned tile[4][16][68];
    __shared__ float bnacc[128];

    const int tid = threadIdx.x;
    const int lane = tid & 63;
    const int wv = tid >> 6;
    const int q = lane >> 4;      // quad
    const int r = lane & 15;      // row-in-quad / col
    const int node0 = blockIdx.x * 64 + wv * 16;
    const bool active = node0 < N_NODES;

    if (tid < 128) bnacc[tid] = 0.0f;

    // BN affine for dim = lane, computed inline from batch stats.
    float scale = 1.0f, shift = 0.0f;
    if (BN) {
        const float inv_n = 1.0f / (float)N_NODES;
        float mean = sums_in[lane] * inv_n;
        float var = sums_in[64 + lane] * inv_n - mean * mean;
        scale = gamma[lane] * rsqrtf(var + BN_EPS);
        shift = fmaf(-mean, scale, beta[lane]);
    }

    f32x4 acc[4];
    float bs[4], bq[4];
#pragma unroll
    for (int nt = 0; nt < 4; ++nt) {
        acc[nt] = (f32x4){0.f, 0.f, 0.f, 0.f};
        bs[nt] = 0.0f; bq[nt] = 0.0f;
    }

    if (active) {
        const float epsv = 1.0f + eps_all[layer];

        // ---- Phase A: gather + self, lane = dim ----
        int dvec = 0;
        if (lane < 16) dvec = deg[node0 + lane];
        // prefetch next node's chunk-0 indices (16 B) one iteration ahead
        uint4 nfA = ((const uint4*)(esrc + (size_t)node0 * PAD))[0];
        for (int i = 0; i < 16; ++i) {
            const uint4 c0v = nfA;
            if (i < 15)
                nfA = ((const uint4*)(esrc + (size_t)(node0 + i + 1) * PAD))[0];
            const int n = node0 + i;
            const int dfull = __builtin_amdgcn_readlane(dvec, i);  // wave-uniform
            const int d = min(dfull, PAD);
            const int dc = (d + 3) >> 2;            // chunks needed, 0..6
            const uint4* ep4 = (const uint4*)(esrc + (size_t)n * PAD);

            float xv = bfu(xb[(size_t)n * 64 + lane]);   // bf16 self term
            if (BN) xv = fmaxf(fmaf(xv, scale, shift), 0.0f);
            float hval = epsv * xv;

            // batch 1: chunks 0..min(dc,3)-1 (c0v pre-loaded)
            switch (dc < 3 ? dc : 3) {
            case 3: hval += gatherN<3, true, BN>(c0v, ep4, 0, xb, lane, scale, shift); break;
            case 2: hval += gatherN<2, true, BN>(c0v, ep4, 0, xb, lane, scale, shift); break;
            case 1: hval += gatherN<1, true, BN>(c0v, ep4, 0, xb, lane, scale, shift); break;
            default: break;                          // deg==0 (P ~ 4.5e-5)
            }
            // batch 2: chunks 3..dc-1 (P(dc>3) ~ 0.21)
            if (dc > 3) {
                switch (dc - 3) {
                case 3: hval += gatherN<3, false, BN>(c0v, ep4, 3, xb, lane, scale, shift); break;
                case 2: hval += gatherN<2, false, BN>(c0v, ep4, 3, xb, lane, scale, shift); break;
                case 1: hval += gatherN<1, false, BN>(c0v, ep4, 3, xb, lane, scale, shift); break;
                default: break;
                }
            }
            if (dfull > PAD) {   // ultra-rare: scan tiny spill list
                int ns = min(*nspill, SPILL_CAP);
                for (int e = 0; e < ns; ++e) {
                    if (spill[2 * e] == n) {
                        float t = bfu(xb[(size_t)spill[2 * e + 1] * 64 + lane]);
                        if (BN) t = fmaxf(fmaf(t, scale, shift), 0.0f);
                        hval += t;
                    }
                }
            }
            __bf16 hi = (__bf16)hval;
            __bf16 lo = (__bf16)(hval - (float)hi);
            tile[wv][i][lane] = ((unsigned)__builtin_bit_cast(unsigned short, hi) << 16)
                              | (unsigned)__builtin_bit_cast(unsigned short, lo);
        }

        // ---- Phase B1: pull BOTH ksteps' A-frags into regs, then GEMM1 ----
        uint4 f0 = *(const uint4*)&tile[wv][r][q * 8];
        uint4 f1 = *(const uint4*)&tile[wv][r][q * 8 + 4];
        uint4 f2 = *(const uint4*)&tile[wv][r][32 + q * 8];
        uint4 f3 = *(const uint4*)&tile[wv][r][32 + q * 8 + 4];
#pragma unroll
        for (int kstep = 0; kstep < 2; ++kstep) {
            uint4 p0 = kstep ? f2 : f0;
            uint4 p1 = kstep ? f3 : f1;
            unsigned pk[8] = {p0.x, p0.y, p0.z, p0.w, p1.x, p1.y, p1.z, p1.w};
            bf16x8 ahi, alo;
#pragma unroll
            for (int j = 0; j < 8; ++j) {
                ahi[j] = __builtin_bit_cast(__bf16, (unsigned short)(pk[j] >> 16));
                alo[j] = __builtin_bit_cast(__bf16, (unsigned short)(pk[j] & 0xffffu));
            }
#pragma unroll
            for (int nt = 0; nt < 4; ++nt) {
                const __bf16* bp = wf1 + ((kstep * 4 + nt) * 64 + lane) * 8;
                bf16x8 bhi = *(const bf16x8*)bp;
                bf16x8 blo = *(const bf16x8*)(bp + 4096);
                acc[nt] = __builtin_amdgcn_mfma_f32_16x16x32_bf16(ahi, bhi, acc[nt], 0, 0, 0);
                acc[nt] = __builtin_amdgcn_mfma_f32_16x16x32_bf16(alo, bhi, acc[nt], 0, 0, 0);
                acc[nt] = __builtin_amdgcn_mfma_f32_16x16x32_bf16(ahi, blo, acc[nt], 0, 0, 0);
            }
        }
        // ---- bias + relu, repack h1 (hi|lo) into the SAME tile ----
#pragma unroll
        for (int nt = 0; nt < 4; ++nt) {
            float b1v = b1[nt * 16 + r];
#pragma unroll
            for (int reg = 0; reg < 4; ++reg) {
                float v = fmaxf(acc[nt][reg] + b1v, 0.0f);
                __bf16 hi = (__bf16)v;
                __bf16 lo = (__bf16)(v - (float)hi);
                unsigned pk = ((unsigned)__builtin_bit_cast(unsigned short, hi) << 16)
                            | (unsigned)__builtin_bit_cast(unsigned short, lo);
                tile[wv][q * 4 + reg][nt * 16 + r] = pk;
            }
            acc[nt] = (f32x4){0.f, 0.f, 0.f, 0.f};
        }
        // ---- Phase B2: GEMM2 from tile ----
#pragma unroll
        for (int kstep = 0; kstep < 2; ++kstep) {
            uint4 p0 = *(const uint4*)&tile[wv][r][kstep * 32 + q * 8];
            uint4 p1 = *(const uint4*)&tile[wv][r][kstep * 32 + q * 8 + 4];
            unsigned pk[8] = {p0.x, p0.y, p0.z, p0.w, p1.x, p1.y, p1.z, p1.w};
            bf16x8 ahi, alo;
#pragma unroll
            for (int j = 0; j < 8; ++j) {
                ahi[j] = __builtin_bit_cast(__bf16, (unsigned short)(pk[j] >> 16));
                alo[j] = __builtin_bit_cast(__bf16, (unsigned short)(pk[j] & 0xffffu));
            }
#pragma unroll
            for (int nt = 0; nt < 4; ++nt) {
                const __bf16* bp = wf2 + ((kstep * 4 + nt) * 64 + lane) * 8;
                bf16x8 bhi = *(const bf16x8*)bp;
                bf16x8 blo = *(const bf16x8*)(bp + 4096);
                acc[nt] = __builtin_amdgcn_mfma_f32_16x16x32_bf16(ahi, bhi, acc[nt], 0, 0, 0);
                acc[nt] = __builtin_amdgcn_mfma_f32_16x16x32_bf16(alo, bhi, acc[nt], 0, 0, 0);
                acc[nt] = __builtin_amdgcn_mfma_f32_16x16x32_bf16(ahi, blo, acc[nt], 0, 0, 0);
            }
        }
        // ---- epilogue: bias + relu, bf16 store, BN partials (fp32) ----
#pragma unroll
        for (int nt = 0; nt < 4; ++nt) {
            float b2v = b2[nt * 16 + r];
#pragma unroll
            for (int reg = 0; reg < 4; ++reg) {
                float v = fmaxf(acc[nt][reg] + b2v, 0.0f);
                size_t oi = (size_t)(node0 + q * 4 + reg) * 64 + nt * 16 + r;
                xbout[oi] = __builtin_bit_cast(unsigned short, (__bf16)v);
                bs[nt] += v;
                bq[nt] = fmaf(v, v, bq[nt]);
            }
        }
    }
    // ---- BN reduction: quads -> wave (shfl), waves -> block (LDS atomics) ----
    __syncthreads();
#pragma unroll
    for (int nt = 0; nt < 4; ++nt) {
        float s = bs[nt];
        s += __shfl_xor(s, 16);
        s += __shfl_xor(s, 32);
        float ss = bq[nt];
        ss += __shfl_xor(ss, 16);
        ss += __shfl_xor(ss, 32);
        if (q == 0) {
            atomicAdd(&bnacc[nt * 16 + r], s);
            atomicAdd(&bnacc[64 + nt * 16 + r], ss);
        }
    }
    __syncthreads();
    if (tid < 128) unsafeAtomicAdd(&sums_out[tid], bnacc[tid]);
}

// ---------------------------------------------------------------------------
// Fused pool + final linear (unchanged).
// ---------------------------------------------------------------------------
__global__ __launch_bounds__(1024) void head_kernel(
    const unsigned short* __restrict__ h2b, const float* __restrict__ sums,
    const float* __restrict__ gamma, const float* __restrict__ beta,
    const int* __restrict__ bstart, const float* __restrict__ lin_w,
    const float* __restrict__ lin_b, float* __restrict__ out)
{
    __shared__ float red[16][64];
    __shared__ float pooled_s[64];
    const int g = blockIdx.x;
    const int tid = threadIdx.x;
    const int lane = tid & 63;
    const int wv = tid >> 6;
    const int lo = bstart[g];
    const int hi = bstart[g + 1];

    const float inv_n = 1.0f / (float)N_NODES;
    float mean = sums[lane] * inv_n;
    float var = sums[64 + lane] * inv_n - mean * mean;
    const float scale = gamma[lane] * rsqrtf(var + BN_EPS);
    const float shift = fmaf(-mean, scale, beta[lane]);

    float acc = 0.0f;
    for (int n = lo + wv; n < hi; n += 16) {
        float v = bfu(h2b[(size_t)n * 64 + lane]);
        acc += fmaxf(fmaf(v, scale, shift), 0.0f);
    }
    red[wv][lane] = acc;
    __syncthreads();
    if (wv == 0) {
        float s = 0.0f;
#pragma unroll
        for (int w = 0; w < 16; ++w) s += red[w][lane];
        float c = fmaxf((float)(hi - lo), 1.0f);
        pooled_s[lane] = s / c;
    }
    __syncthreads();
    if (tid < OUT_DIM) {
        float a2 = lin_b[tid];
#pragma unroll
        for (int d = 0; d < 64; ++d)
            a2 = fmaf(pooled_s[d], lin_w[d * OUT_DIM + tid], a2);
        out[g * OUT_DIM + tid] = a2;
    }
}

extern "C" void kernel_launch(void* const* d_in, const int* in_sizes, int n_in,
                              void* d_out, int out_size, void* d_ws, size_t ws_size,
                              hipStream_t stream)
{
    const float* x0    = (const float*)d_in[0];
    const int*   ei    = (const int*)d_in[1];
    const int*   batch = (const int*)d_in[2];
    const float* w1    = (const float*)d_in[3];
    const float* b1    = (const float*)d_in[4];
    const float* w2    = (const float*)d_in[5];
    const float* b2    = (const float*)d_in[6];
    const float* gamma = (const float*)d_in[7];
    const float* beta  = (const float*)d_in[8];
    const float* eps_g = (const float*)d_in[9];
    const float* lin_w = (const float*)d_in[10];
    const float* lin_b = (const float*)d_in[11];
    float* out = (float*)d_out;

    // Workspace layout — unchanged.
    float* ws   = (float*)d_ws;
    float* SUMS = ws;                                // 3*128
    float* POOL = SUMS + 384;                        // 16384 (BSTART lives here)
    float* CNT  = POOL + N_GRAPHS * 64;              // 256 (unused, layout pad)
    int*   DEG    = (int*)(CNT + N_GRAPHS);          // 100000
    int*   NSPILL = DEG + N_NODES;                   // 16
    int*   PFCNT  = NSPILL + 16;                     // 16 (unused, layout pad)
    __bf16* WF  = (__bf16*)(PFCNT + 16);             // 6*8192 bf16 = 96 KB
    int*   SPILL  = (int*)(WF + 6 * 8192);           // 2*SPILL_CAP
    int*   ESRC   = SPILL + 2 * SPILL_CAP;           // 24*N = 9.6 MB
    unsigned short* XP = (unsigned short*)(ESRC + (size_t)N_NODES * PAD);
    unsigned short* XQ = XP + (size_t)(N_NODES + 1) * 64;   // each: (N+1) rows
    unsigned short* XS = XQ + (size_t)(N_NODES + 1) * 64;
    unsigned short* XR = XS + (size_t)(N_NODES + 1) * 64;

    int* BSTART = (int*)POOL;          // 257 ints

    // ---- minimal zero + segment boundaries ----
    zero_kernel<<<ZERO_BLOCKS, 256, 0, stream>>>(
        (uint4*)SUMS, (uint4*)DEG, batch, BSTART);

    // ---- grid-stride XCD-partitioned fill, prep-compute fused in-grid ----
    fill_kernel<<<FF_BLOCKS, 256, 0, stream>>>(
        ei, DEG, ESRC, NSPILL, SPILL,
        w1, w2, WF, (const float4*)x0, (ushort4*)XP,
        XP + (size_t)N_NODES * 64, XQ + (size_t)N_NODES * 64,
        XS + (size_t)N_NODES * 64);

    // ---- 3 fused GIN layers (BN of layer L folded into layer L+1) ----
    layer_kernel<false><<<LAYER_BLOCKS, 256, 0, stream>>>(
        XP, nullptr, nullptr, nullptr, DEG, ESRC, NSPILL, SPILL, XQ,
        WF, WF + 8192, b1, b2, eps_g, 0, SUMS);

    layer_kernel<true><<<LAYER_BLOCKS, 256, 0, stream>>>(
        XQ, SUMS, gamma, beta, DEG, ESRC, NSPILL, SPILL, XS,
        WF + 16384, WF + 24576, b1 + 64, b2 + 64, eps_g, 1, SUMS + 128);

    layer_kernel<true><<<LAYER_BLOCKS, 256, 0, stream>>>(
        XS, SUMS + 128, gamma + 64, beta + 64, DEG, ESRC, NSPILL, SPILL, XR,
        WF + 32768, WF + 40960, b1 + 128, b2 + 128, eps_g, 2, SUMS + 256);

    // ---- fused pool + final linear ----
    head_kernel<<<N_GRAPHS, 1024, 0, stream>>>(
        XR, SUMS + 256, gamma + 128, beta + 128, BSTART, lin_w, lin_b, out);
}

// Round 5
// 333.588 us; speedup vs baseline: 1.1296x; 1.1296x over previous
//
#include <hip/hip_runtime.h>
#include <hip/hip_bf16.h>

#define N_NODES 100000
#define N_EDGES 1000000
#define DIM 64
#define N_GRAPHS 256
#define OUT_DIM 10
#define BN_EPS 1e-5f

#define LAYER_BLOCKS ((N_NODES + 63) / 64)   // 1563 (4-wave blocks — R12 form)
#define PAD 24                               // slots per node; P(deg>24)~4e-5
#define SPILL_CAP 8192
#define NPART 8                              // dst partitions (one per XCD)
#define PART_SZ ((N_NODES + NPART - 1) / NPART)   // 12500

// ---- fused fill grid: proven R6 fill blocks FIRST (XCD map preserved),
// then the prep-compute blocks (x-convert, weight split, sentinels) ----
#define FILL_BLOCKS (((N_EDGES + 255) / 256) * NPART)          // 31256
#define XC_BLOCKS ((N_NODES * 16 + 255) / 256)                 // 6250
#define FF_BLOCKS (FILL_BLOCKS + XC_BLOCKS + 6 + 1)            // 37513

// ---- zero kernel geometry ----
#define Z4A 96                       // SUMS: 384 floats as uint4
#define Z4B 25008                    // DEG+NSPILL+PFCNT: 100032 ints as uint4
#define ZLIN_BLOCKS ((Z4A + Z4B + 255) / 256)                  // 99
#define SEG_BLOCKS ((N_NODES + 255) / 256)                     // 391
#define ZERO_BLOCKS (ZLIN_BLOCKS + SEG_BLOCKS)                 // 490

typedef __bf16 bf16x8 __attribute__((ext_vector_type(8)));
typedef float f32x4 __attribute__((ext_vector_type(4)));

__device__ __forceinline__ float bfu(unsigned short u) {
    return (float)__builtin_bit_cast(__bf16, u);
}

// ---------------------------------------------------------------------------
// Zero + segment-boundary kernel (tiny; precedes everything).
//   blocks [0,ZLIN): zero SUMS (384 f) and DEG/NSPILL/PFCNT (100032 i)
//   blocks [ZLIN,+SEG): BSTART[g] = first node of graph g (batch sorted);
//                       BSTART[256] = N_NODES. Removes per-graph search in head.
// ---------------------------------------------------------------------------
__global__ __launch_bounds__(256) void zero_kernel(
    uint4* __restrict__ za, uint4* __restrict__ zb,
    const int* __restrict__ batch, int* __restrict__ bstart)
{
    const int bid = blockIdx.x;
    const int tid = threadIdx.x;
    if (bid < ZLIN_BLOCKS) {
        int i = bid * 256 + tid;
        uint4 z = {0u, 0u, 0u, 0u};
        if (i < Z4A) za[i] = z;
        else if (i < Z4A + Z4B) zb[i - Z4A] = z;
    } else {
        int n = (bid - ZLIN_BLOCKS) * 256 + tid;
        if (n < N_NODES) {
            int b = batch[n];
            int bp = (n == 0) ? -1 : batch[n - 1];
            for (int gg = bp + 1; gg <= b; ++gg) bstart[gg] = n;
            if (n == N_NODES - 1)
                for (int gg = b + 1; gg <= N_GRAPHS; ++gg) bstart[gg] = N_NODES;
        }
    }
}

// ---------------------------------------------------------------------------
// Fused fill + prep-compute — R2 measured-best form (334.6 us total).
// R1 post-mortem: two-stage bucket scheme (single-line pfcnt atomics +
// 8.4 MB buck round-trip) was ~30 us SLOWER — the 8x rescans are L3-absorbed.
// R3 post-mortem: grid-stride variant neutral (fill is transaction-bound,
// not dispatch-bound). Fill body is the proven R6 scheme VERBATIM (blocks
// [0,FILL)), part->XCD mapping preserved. Prep compute (x-convert, weight
// split, sentinels) rides AFTER the fill blocks in the same grid; only the
// tiny zero_kernel must precede this launch.
// ---------------------------------------------------------------------------
__global__ __launch_bounds__(256) void fill_kernel(
    const int* __restrict__ ei, int* __restrict__ deg,
    int* __restrict__ esrc, int* __restrict__ nspill, int* __restrict__ spill,
    const float* __restrict__ w1, const float* __restrict__ w2,
    __bf16* __restrict__ wf,
    const float4* __restrict__ x0, ushort4* __restrict__ xp4,
    unsigned short* __restrict__ xp_s, unsigned short* __restrict__ xq_s,
    unsigned short* __restrict__ xs_s)
{
    const int bid = blockIdx.x;
    const int tid = threadIdx.x;

    if (bid < FILL_BLOCKS) {
        // ---- proven R6 XCD-partitioned edge fill (byte-identical logic) ----
        const int part = bid & (NPART - 1);
        const int e = (bid >> 3) * 256 + tid;
        if (e >= N_EDGES) return;
        int dst = ei[N_EDGES + e];
        int lo = part * PART_SZ;
        if (dst < lo || dst >= lo + PART_SZ) return;
        int src = ei[e];
        int pos = atomicAdd(&deg[dst], 1);
        if (pos < PAD) {
            esrc[dst * PAD + pos] = src;
        } else {
            int sp = atomicAdd(nspill, 1);
            if (sp < SPILL_CAP) { spill[2 * sp] = dst; spill[2 * sp + 1] = src; }
        }
    } else if (bid < FILL_BLOCKS + XC_BLOCKS) {
        // ---- x0 -> bf16 copy XP ----
        int t = (bid - FILL_BLOCKS) * 256 + tid;
        if (t < N_NODES * 16) {
            float4 v = x0[t];
            ushort4 o;
            o.x = __builtin_bit_cast(unsigned short, (__bf16)v.x);
            o.y = __builtin_bit_cast(unsigned short, (__bf16)v.y);
            o.z = __builtin_bit_cast(unsigned short, (__bf16)v.z);
            o.w = __builtin_bit_cast(unsigned short, (__bf16)v.w);
            xp4[t] = o;
        }
    } else if (bid < FILL_BLOCKS + XC_BLOCKS + 6) {
        // ---- weight split: fp32 W -> bf16 hi/lo, MFMA B-frag order ----
        int wb = bid - FILL_BLOCKS - XC_BLOCKS;
        int L = wb >> 1, mat = wb & 1;
        const float* w = (mat ? w2 : w1) + L * 4096;
        __bf16* dst = wf + wb * 8192;
#pragma unroll
        for (int r = 0; r < 2; ++r) {
            int idx = tid + 256 * r;              // (kstep*4+nt)*64 + lane
            int lane = idx & 63;
            int kt = idx >> 6;
            int kstep = kt >> 2, nt = kt & 3;
            int n = nt * 16 + (lane & 15);
            int kbase = kstep * 32 + (lane >> 4) * 8;
#pragma unroll
            for (int j = 0; j < 8; ++j) {
                float v = w[(kbase + j) * 64 + n];
                __bf16 hi = (__bf16)v;
                dst[idx * 8 + j] = hi;
                dst[4096 + idx * 8 + j] = (__bf16)(v - (float)hi);
            }
        }
    } else {
        // ---- sentinel rows: XP[N]=0, XQ[N]=XS[N]=bf16(-inf) ----
        if (tid < 64) {
            xp_s[tid] = 0;                        // bf16 +0
            xq_s[tid] = 0xFF80;                   // bf16 -inf
            xs_s[tid] = 0xFF80;
        }
    }
}

// ---------------------------------------------------------------------------
// FUSED GIN layer — verified R12 structure, BYTE-IDENTICAL to the 334.6 us
// measurement. At the random-gather latency floor — evidence now TWO-SIDED:
// scheduling attacks (occupancy/prefetch/dual-row, prior session) regressed,
// and traffic reduction (R4 variable-length 4-slot gather, -21% lines)
// regressed 19% with FETCH unchanged (rows were L3-hits; fixed-12 burst's
// branch-free MLP is what sets the pace). DO NOT TOUCH.
// ---------------------------------------------------------------------------
template <bool BN>
__global__ __launch_bounds__(256) void layer_kernel(
    const unsigned short* __restrict__ xb,
    const float* __restrict__ sums_in, const float* __restrict__ gamma,
    const float* __restrict__ beta,
    const int* __restrict__ deg, const int* __restrict__ esrc,
    const int* __restrict__ nspill, const int* __restrict__ spill,
    unsigned short* __restrict__ xbout,
    const __bf16* __restrict__ wf1, const __bf16* __restrict__ wf2,
    const float* __restrict__ b1, const float* __restrict__ b2,
    const float* __restrict__ eps_all, int layer,
    float* __restrict__ sums_out)
{
    __shared__ __attribute__((aligned(16))) unsigned tile[4][16][68];
    __shared__ float bnacc[128];

    const int tid = threadIdx.x;
    const int lane = tid & 63;
    const int wv = tid >> 6;
    const int q = lane >> 4;      // quad
    const int r = lane & 15;      // row-in-quad / col
    const int node0 = blockIdx.x * 64 + wv * 16;
    const bool active = node0 < N_NODES;

    if (tid < 128) bnacc[tid] = 0.0f;

    // BN affine for dim = lane, computed inline from batch stats.
    float scale = 1.0f, shift = 0.0f;
    if (BN) {
        const float inv_n = 1.0f / (float)N_NODES;
        float mean = sums_in[lane] * inv_n;
        float var = sums_in[64 + lane] * inv_n - mean * mean;
        scale = gamma[lane] * rsqrtf(var + BN_EPS);
        shift = fmaf(-mean, scale, beta[lane]);
    }

    f32x4 acc[4];
    float bs[4], bq[4];
#pragma unroll
    for (int nt = 0; nt < 4; ++nt) {
        acc[nt] = (f32x4){0.f, 0.f, 0.f, 0.f};
        bs[nt] = 0.0f; bq[nt] = 0.0f;
    }

    if (active) {
        const float epsv = 1.0f + eps_all[layer];

        // ---- Phase A: gather + self, lane = dim ----
        int dvec = 0;
        if (lane < 16) dvec = deg[node0 + lane];
        uint4 nf0, nf1, nf2;
        {
            const uint4* ip = (const uint4*)(esrc + (size_t)node0 * PAD);
            nf0 = ip[0]; nf1 = ip[1]; nf2 = ip[2];
        }
        for (int i = 0; i < 16; ++i) {
            const uint4 c0 = nf0, c1 = nf1, c2 = nf2;
            if (i < 15) {   // issue next node's idx loads before consuming
                const uint4* ip = (const uint4*)(esrc + (size_t)(node0 + i + 1) * PAD);
                nf0 = ip[0]; nf1 = ip[1]; nf2 = ip[2];
            }
            const int n = node0 + i;
            const int dfull = __builtin_amdgcn_readlane(dvec, i);  // wave-uniform
            const int d = min(dfull, PAD);

            float xv = bfu(xb[(size_t)n * 64 + lane]);   // bf16 self term
            if (BN) xv = fmaxf(fmaf(xv, scale, shift), 0.0f);
            float hval = epsv * xv;

            {   // chunk 0: slots 0..11; pad slots hit the sentinel row (-> +0)
                unsigned idx[12] = {c0.x, c0.y, c0.z, c0.w, c1.x, c1.y,
                                    c1.z, c1.w, c2.x, c2.y, c2.z, c2.w};
                unsigned short u[12];
#pragma unroll
                for (int j = 0; j < 12; ++j) {
                    unsigned s = idx[j];
                    s = (s < (unsigned)N_NODES) ? s : (unsigned)N_NODES;
                    u[j] = xb[(size_t)s * 64 + lane];
                }
#pragma unroll
                for (int j = 0; j < 12; ++j) {
                    float t = bfu(u[j]);
                    if (BN) t = fmaxf(fmaf(t, scale, shift), 0.0f);
                    hval += t;
                }
            }
            if (d > 12) {   // chunk 1: slots 12..23 (wave-uniform branch)
                const int* ep = esrc + (size_t)n * PAD + 12;
                unsigned short u[12];
#pragma unroll
                for (int j = 0; j < 12; ++j) {
                    unsigned s = (unsigned)ep[j];
                    s = (s < (unsigned)N_NODES) ? s : (unsigned)N_NODES;
                    u[j] = xb[(size_t)s * 64 + lane];
                }
#pragma unroll
                for (int j = 0; j < 12; ++j) {
                    float t = bfu(u[j]);
                    if (BN) t = fmaxf(fmaf(t, scale, shift), 0.0f);
                    hval += t;
                }
            }
            if (dfull > PAD) {   // ultra-rare: scan tiny spill list
                int ns = min(*nspill, SPILL_CAP);
                for (int e = 0; e < ns; ++e) {
                    if (spill[2 * e] == n) {
                        float t = bfu(xb[(size_t)spill[2 * e + 1] * 64 + lane]);
                        if (BN) t = fmaxf(fmaf(t, scale, shift), 0.0f);
                        hval += t;
                    }
                }
            }
            __bf16 hi = (__bf16)hval;
            __bf16 lo = (__bf16)(hval - (float)hi);
            tile[wv][i][lane] = ((unsigned)__builtin_bit_cast(unsigned short, hi) << 16)
                              | (unsigned)__builtin_bit_cast(unsigned short, lo);
        }

        // ---- Phase B1: pull BOTH ksteps' A-frags into regs, then GEMM1 ----
        uint4 f0 = *(const uint4*)&tile[wv][r][q * 8];
        uint4 f1 = *(const uint4*)&tile[wv][r][q * 8 + 4];
        uint4 f2 = *(const uint4*)&tile[wv][r][32 + q * 8];
        uint4 f3 = *(const uint4*)&tile[wv][r][32 + q * 8 + 4];
#pragma unroll
        for (int kstep = 0; kstep < 2; ++kstep) {
            uint4 p0 = kstep ? f2 : f0;
            uint4 p1 = kstep ? f3 : f1;
            unsigned pk[8] = {p0.x, p0.y, p0.z, p0.w, p1.x, p1.y, p1.z, p1.w};
            bf16x8 ahi, alo;
#pragma unroll
            for (int j = 0; j < 8; ++j) {
                ahi[j] = __builtin_bit_cast(__bf16, (unsigned short)(pk[j] >> 16));
                alo[j] = __builtin_bit_cast(__bf16, (unsigned short)(pk[j] & 0xffffu));
            }
#pragma unroll
            for (int nt = 0; nt < 4; ++nt) {
                const __bf16* bp = wf1 + ((kstep * 4 + nt) * 64 + lane) * 8;
                bf16x8 bhi = *(const bf16x8*)bp;
                bf16x8 blo = *(const bf16x8*)(bp + 4096);
                acc[nt] = __builtin_amdgcn_mfma_f32_16x16x32_bf16(ahi, bhi, acc[nt], 0, 0, 0);
                acc[nt] = __builtin_amdgcn_mfma_f32_16x16x32_bf16(alo, bhi, acc[nt], 0, 0, 0);
                acc[nt] = __builtin_amdgcn_mfma_f32_16x16x32_bf16(ahi, blo, acc[nt], 0, 0, 0);
            }
        }
        // ---- bias + relu, repack h1 (hi|lo) into the SAME tile ----
#pragma unroll
        for (int nt = 0; nt < 4; ++nt) {
            float b1v = b1[nt * 16 + r];
#pragma unroll
            for (int reg = 0; reg < 4; ++reg) {
                float v = fmaxf(acc[nt][reg] + b1v, 0.0f);
                __bf16 hi = (__bf16)v;
                __bf16 lo = (__bf16)(v - (float)hi);
                unsigned pk = ((unsigned)__builtin_bit_cast(unsigned short, hi) << 16)
                            | (unsigned)__builtin_bit_cast(unsigned short, lo);
                tile[wv][q * 4 + reg][nt * 16 + r] = pk;
            }
            acc[nt] = (f32x4){0.f, 0.f, 0.f, 0.f};
        }
        // ---- Phase B2: GEMM2 from tile ----
#pragma unroll
        for (int kstep = 0; kstep < 2; ++kstep) {
            uint4 p0 = *(const uint4*)&tile[wv][r][kstep * 32 + q * 8];
            uint4 p1 = *(const uint4*)&tile[wv][r][kstep * 32 + q * 8 + 4];
            unsigned pk[8] = {p0.x, p0.y, p0.z, p0.w, p1.x, p1.y, p1.z, p1.w};
            bf16x8 ahi, alo;
#pragma unroll
            for (int j = 0; j < 8; ++j) {
                ahi[j] = __builtin_bit_cast(__bf16, (unsigned short)(pk[j] >> 16));
                alo[j] = __builtin_bit_cast(__bf16, (unsigned short)(pk[j] & 0xffffu));
            }
#pragma unroll
            for (int nt = 0; nt < 4; ++nt) {
                const __bf16* bp = wf2 + ((kstep * 4 + nt) * 64 + lane) * 8;
                bf16x8 bhi = *(const bf16x8*)bp;
                bf16x8 blo = *(const bf16x8*)(bp + 4096);
                acc[nt] = __builtin_amdgcn_mfma_f32_16x16x32_bf16(ahi, bhi, acc[nt], 0, 0, 0);
                acc[nt] = __builtin_amdgcn_mfma_f32_16x16x32_bf16(alo, bhi, acc[nt], 0, 0, 0);
                acc[nt] = __builtin_amdgcn_mfma_f32_16x16x32_bf16(ahi, blo, acc[nt], 0, 0, 0);
            }
        }
        // ---- epilogue: bias + relu, bf16 store, BN partials (fp32) ----
#pragma unroll
        for (int nt = 0; nt < 4; ++nt) {
            float b2v = b2[nt * 16 + r];
#pragma unroll
            for (int reg = 0; reg < 4; ++reg) {
                float v = fmaxf(acc[nt][reg] + b2v, 0.0f);
                size_t oi = (size_t)(node0 + q * 4 + reg) * 64 + nt * 16 + r;
                xbout[oi] = __builtin_bit_cast(unsigned short, (__bf16)v);
                bs[nt] += v;
                bq[nt] = fmaf(v, v, bq[nt]);
            }
        }
    }
    // ---- BN reduction: quads -> wave (shfl), waves -> block (LDS atomics) ----
    __syncthreads();
#pragma unroll
    for (int nt = 0; nt < 4; ++nt) {
        float s = bs[nt];
        s += __shfl_xor(s, 16);
        s += __shfl_xor(s, 32);
        float ss = bq[nt];
        ss += __shfl_xor(ss, 16);
        ss += __shfl_xor(ss, 32);
        if (q == 0) {
            atomicAdd(&bnacc[nt * 16 + r], s);
            atomicAdd(&bnacc[64 + nt * 16 + r], ss);
        }
    }
    __syncthreads();
    if (tid < 128) unsafeAtomicAdd(&sums_out[tid], bnacc[tid]);
}

// ---------------------------------------------------------------------------
// Fused pool + final linear: one block per graph (segment bounds from BSTART,
// precomputed in zero_kernel — no binary search, no POOL/CNT atomics).
// 16 waves stream the segment; LDS reduce; threads 0..9 do the 64x10 linear.
// ---------------------------------------------------------------------------
__global__ __launch_bounds__(1024) void head_kernel(
    const unsigned short* __restrict__ h2b, const float* __restrict__ sums,
    const float* __restrict__ gamma, const float* __restrict__ beta,
    const int* __restrict__ bstart, const float* __restrict__ lin_w,
    const float* __restrict__ lin_b, float* __restrict__ out)
{
    __shared__ float red[16][64];
    __shared__ float pooled_s[64];
    const int g = blockIdx.x;
    const int tid = threadIdx.x;
    const int lane = tid & 63;
    const int wv = tid >> 6;
    const int lo = bstart[g];
    const int hi = bstart[g + 1];

    const float inv_n = 1.0f / (float)N_NODES;
    float mean = sums[lane] * inv_n;
    float var = sums[64 + lane] * inv_n - mean * mean;
    const float scale = gamma[lane] * rsqrtf(var + BN_EPS);
    const float shift = fmaf(-mean, scale, beta[lane]);

    float acc = 0.0f;
    for (int n = lo + wv; n < hi; n += 16) {
        float v = bfu(h2b[(size_t)n * 64 + lane]);
        acc += fmaxf(fmaf(v, scale, shift), 0.0f);
    }
    red[wv][lane] = acc;
    __syncthreads();
    if (wv == 0) {
        float s = 0.0f;
#pragma unroll
        for (int w = 0; w < 16; ++w) s += red[w][lane];
        float c = fmaxf((float)(hi - lo), 1.0f);
        pooled_s[lane] = s / c;
    }
    __syncthreads();
    if (tid < OUT_DIM) {
        float a2 = lin_b[tid];
#pragma unroll
        for (int d = 0; d < 64; ++d)
            a2 = fmaf(pooled_s[d], lin_w[d * OUT_DIM + tid], a2);
        out[g * OUT_DIM + tid] = a2;
    }
}

extern "C" void kernel_launch(void* const* d_in, const int* in_sizes, int n_in,
                              void* d_out, int out_size, void* d_ws, size_t ws_size,
                              hipStream_t stream)
{
    const float* x0    = (const float*)d_in[0];
    const int*   ei    = (const int*)d_in[1];
    const int*   batch = (const int*)d_in[2];
    const float* w1    = (const float*)d_in[3];
    const float* b1    = (const float*)d_in[4];
    const float* w2    = (const float*)d_in[5];
    const float* b2    = (const float*)d_in[6];
    const float* gamma = (const float*)d_in[7];
    const float* beta  = (const float*)d_in[8];
    const float* eps_g = (const float*)d_in[9];
    const float* lin_w = (const float*)d_in[10];
    const float* lin_b = (const float*)d_in[11];
    float* out = (float*)d_out;

    // Workspace layout — byte-identical to R15 (layers measured 67 us under
    // it). POOL hosts BSTART[257]; PFCNT retained as layout pad.
    float* ws   = (float*)d_ws;
    float* SUMS = ws;                                // 3*128
    float* POOL = SUMS + 384;                        // 16384 (BSTART lives here)
    float* CNT  = POOL + N_GRAPHS * 64;              // 256 (unused, layout pad)
    int*   DEG    = (int*)(CNT + N_GRAPHS);          // 100000
    int*   NSPILL = DEG + N_NODES;                   // 16
    int*   PFCNT  = NSPILL + 16;                     // 16 (unused, layout pad)
    __bf16* WF  = (__bf16*)(PFCNT + 16);             // 6*8192 bf16 = 96 KB
    int*   SPILL  = (int*)(WF + 6 * 8192);           // 2*SPILL_CAP
    int*   ESRC   = SPILL + 2 * SPILL_CAP;           // 24*N = 9.6 MB
    unsigned short* XP = (unsigned short*)(ESRC + (size_t)N_NODES * PAD);
    unsigned short* XQ = XP + (size_t)(N_NODES + 1) * 64;   // each: (N+1) rows
    unsigned short* XS = XQ + (size_t)(N_NODES + 1) * 64;
    unsigned short* XR = XS + (size_t)(N_NODES + 1) * 64;

    int* BSTART = (int*)POOL;          // 257 ints

    // ---- minimal zero + segment boundaries ----
    zero_kernel<<<ZERO_BLOCKS, 256, 0, stream>>>(
        (uint4*)SUMS, (uint4*)DEG, batch, BSTART);

    // ---- proven 8-pass XCD-partitioned fill, prep-compute fused in-grid ----
    fill_kernel<<<FF_BLOCKS, 256, 0, stream>>>(
        ei, DEG, ESRC, NSPILL, SPILL,
        w1, w2, WF, (const float4*)x0, (ushort4*)XP,
        XP + (size_t)N_NODES * 64, XQ + (size_t)N_NODES * 64,
        XS + (size_t)N_NODES * 64);

    // ---- 3 fused GIN layers (BN of layer L folded into layer L+1) ----
    layer_kernel<false><<<LAYER_BLOCKS, 256, 0, stream>>>(
        XP, nullptr, nullptr, nullptr, DEG, ESRC, NSPILL, SPILL, XQ,
        WF, WF + 8192, b1, b2, eps_g, 0, SUMS);

    layer_kernel<true><<<LAYER_BLOCKS, 256, 0, stream>>>(
        XQ, SUMS, gamma, beta, DEG, ESRC, NSPILL, SPILL, XS,
        WF + 16384, WF + 24576, b1 + 64, b2 + 64, eps_g, 1, SUMS + 128);

    layer_kernel<true><<<LAYER_BLOCKS, 256, 0, stream>>>(
        XS, SUMS + 128, gamma + 64, beta + 64, DEG, ESRC, NSPILL, SPILL, XR,
        WF + 32768, WF + 40960, b1 + 128, b2 + 128, eps_g, 2, SUMS + 256);

    // ---- fused pool + final linear ----
    head_kernel<<<N_GRAPHS, 1024, 0, stream>>>(
        XR, SUMS + 256, gamma + 128, beta + 128, BSTART, lin_w, lin_b, out);
}